// Round 6
// baseline (266.282 us; speedup 1.0000x reference)
//
#include <hip/hip_runtime.h>
#include <cstdint>
#include <cstddef>

// Problem dims (fixed by the reference): B=64, S=512, D=768, C=512
#define BB 64
#define SS 512
#define DD 768
#define CC 512

typedef __attribute__((ext_vector_type(8))) short short8;
typedef __attribute__((ext_vector_type(4))) float f32x4;

#define GLOBAL_AS __attribute__((address_space(1)))
#define LDS_AS __attribute__((address_space(3)))

// float -> bf16 bits, round-to-nearest-even
static __device__ __forceinline__ unsigned short f2bf(float f) {
  union { float f; unsigned u; } v; v.f = f;
  unsigned u = v.u;
  u += 0x7FFFu + ((u >> 16) & 1u);
  return (unsigned short)(u >> 16);
}

// async 16B/lane global->LDS copy (wave-uniform LDS base + lane*16)
static __device__ __forceinline__ void async_copy16(const void* g, void* l) {
  __builtin_amdgcn_global_load_lds((const GLOBAL_AS void*)g, (LDS_AS void*)l,
                                   16, 0, 0);
}

// ---------------------------------------------------------------------------
// Kernel 1: normalize label embeddings -> bf16, FRAGMENT-LINEAR layout.
// Per 16-class chunk (chunk = c>>4), element [class mr=c&15][d] is stored at
// ushort offset  chunk*12288 + kc*512 + q*128 + mr*8 + j   where
// kc = d>>5, q = (d>>3)&3, j = d&7.
// The 64 lanes of a wave reading MFMA B-fragments for K-slice kc then read
// 1024 CONSECUTIVE bytes (addr = lane*16 + kc*1024): zero bank conflicts
// (verified round 4: SQ_LDS_BANK_CONFLICT 6.29M -> 0).
// ---------------------------------------------------------------------------
__global__ __launch_bounds__(256) void k_label_norm(const float* __restrict__ L,
                                                    unsigned short* __restrict__ Lnb) {
  const int c = blockIdx.x;
  const int tid = threadIdx.x;
  const float* row = L + (size_t)c * DD;
  float v[3];
  float s = 0.f;
#pragma unroll
  for (int k = 0; k < 3; k++) { v[k] = row[tid + 256 * k]; s += v[k] * v[k]; }
#pragma unroll
  for (int o = 32; o > 0; o >>= 1) s += __shfl_xor(s, o, 64);
  __shared__ float wsum[4];
  if ((tid & 63) == 0) wsum[tid >> 6] = s;
  __syncthreads();
  const float tot = wsum[0] + wsum[1] + wsum[2] + wsum[3];
  const float inv = 1.f / fmaxf(sqrtf(tot), 1e-8f);
  unsigned short* ochunk = Lnb + (size_t)(c >> 4) * (16 * DD);
  const int mr = c & 15;
#pragma unroll
  for (int k = 0; k < 3; k++) {
    const int d = tid + 256 * k;
    const int kc = d >> 5;
    const int q = (d >> 3) & 3;
    const int j = d & 7;
    ochunk[kc * 512 + q * 128 + mr * 8 + j] = f2bf(v[k] * inv);
  }
}

// ---------------------------------------------------------------------------
// Kernel 2: m[b,s] = max_c dot(V[b,s,:], Ln[c,:]) / max(||V||,eps)
// 512 blocks x 4 waves x 16 tokens; A-fragments (24 x short8 = 96 VGPR) in
// registers; fragment-linear Lnb (round 4: zero bank conflicts); VGPR <= 128
// (crossing 128 halves occupancy, measured round 3).
// NEW (round 6): T3+T4 pipeline. Rounds 3/5 proved the compute phase is not
// critical-path (ILP changes were null); the cost is the per-iteration
// __syncthreads vmcnt(0) drain exposing a loaded L2 round-trip for the
// prefetch issued the SAME iteration. Now: 3 LDS buffers, stage chunk cc+2
// each iteration, barrier = s_waitcnt vmcnt(6) + raw s_barrier (+sched
// fence): the newest 6 loads stay in flight ACROSS the barrier, so staging
// latency hides under a full iteration of compute.
// Also: chunk visit order rotated by blockIdx&31 (max is order-independent)
// so 512 blocks don't all hammer the same 24KB L2 lines each step.
// ---------------------------------------------------------------------------
__global__ __launch_bounds__(256) void k_sims_max(const float* __restrict__ V,
                                                  const unsigned short* __restrict__ Lnb,
                                                  float* __restrict__ m_out) {
  const int tid = threadIdx.x;
  const int wave = tid >> 6;
  const int lane = tid & 63;
  const int q = lane >> 4;    // quad 0..3 (K-slice of the fragment)
  const int mr = lane & 15;   // row (token) for A, col (class) for B
  const int64_t tokBase = (int64_t)blockIdx.x * 64 + wave * 16;
  const int rot = blockIdx.x & 31;  // per-block chunk-order rotation

  __shared__ unsigned short Bs[3][16 * DD];  // 3 x 24576 B
  __shared__ float nrmS[4][16];

#define STAGE_CHUNK(chunk, bufidx)                                        \
  {                                                                       \
    const char* src_ = (const char*)(Lnb + (size_t)(chunk) * 16 * DD);    \
    char* dst_ = (char*)&Bs[bufidx][0];                                   \
    _Pragma("unroll")                                                     \
    for (int i_ = wave; i_ < 24; i_ += 4)                                 \
      async_copy16(src_ + i_ * 1024 + lane * 16, dst_ + i_ * 1024);       \
  }

  // ---- prologue: stage chunks rot, rot+1 into buf 0,1 (in flight during A load)
  STAGE_CHUNK(rot, 0);
  STAGE_CHUNK((rot + 1) & 31, 1);

  // ---- load A fragments + squared norm
  const float* arow = V + (tokBase + mr) * DD + q * 8;
  short8 afrag[24];
  float nrm2 = 0.f;
#pragma unroll
  for (int kc = 0; kc < 24; kc++) {
    const float4* p = (const float4*)(arow + kc * 32);
    const float4 x = p[0];
    const float4 y = p[1];
    short8 a;
    a[0] = (short)f2bf(x.x); a[1] = (short)f2bf(x.y);
    a[2] = (short)f2bf(x.z); a[3] = (short)f2bf(x.w);
    a[4] = (short)f2bf(y.x); a[5] = (short)f2bf(y.y);
    a[6] = (short)f2bf(y.z); a[7] = (short)f2bf(y.w);
    afrag[kc] = a;
    nrm2 += x.x * x.x + x.y * x.y + x.z * x.z + x.w * x.w;
    nrm2 += y.x * y.x + y.y * y.y + y.z * y.z + y.w * y.w;
  }
  // lanes {m, m+16, m+32, m+48} each hold 1/4 of token m's sum of squares
  nrm2 += __shfl_xor(nrm2, 16, 64);
  nrm2 += __shfl_xor(nrm2, 32, 64);
  if (q == 0) nrmS[wave][mr] = nrm2;

  __syncthreads();  // full drain once: buf0/buf1 staged + nrmS visible

  const int laneByte = lane * 16;  // fragment-linear: lane's 16B within a K-slice
  f32x4 vmax = {-3e38f, -3e38f, -3e38f, -3e38f};
  int bi = 0;  // buffer holding chunk for iteration cc
  int bs = 2;  // buffer to stage chunk cc+2 into
  for (int cc = 0; cc < 32; cc++) {
    // stage chunk cc+2 into the buffer last read at iteration cc-1
    // (its readers finished before the barrier that ended cc-1)
    if (cc + 2 < 32) STAGE_CHUNK((cc + 2 + rot) & 31, bs);

    f32x4 acc = {0.f, 0.f, 0.f, 0.f};
    const char* bbase = (const char*)&Bs[bi][0] + laneByte;
    // depth-4 rotating B-fragment pipeline (neutral r5, kept)
    short8 bf[4];
#pragma unroll
    for (int j = 0; j < 4; j++) bf[j] = *(const short8*)(bbase + j * 1024);
#pragma unroll
    for (int kc = 0; kc < 24; kc++) {
      acc = __builtin_amdgcn_mfma_f32_16x16x32_bf16(afrag[kc], bf[kc & 3], acc, 0, 0, 0);
      if (kc + 4 < 24) bf[kc & 3] = *(const short8*)(bbase + (kc + 4) * 1024);
    }
    vmax[0] = fmaxf(vmax[0], acc[0]);
    vmax[1] = fmaxf(vmax[1], acc[1]);
    vmax[2] = fmaxf(vmax[2], acc[2]);
    vmax[3] = fmaxf(vmax[3], acc[3]);

    if (cc < 31) {
      // counted drain: keep the newest 6 loads (chunk cc+2) in flight across
      // the barrier; chunk cc+1 (issued at iter cc-1) is verified retired.
      if (cc + 2 < 32) {
        asm volatile("s_waitcnt vmcnt(6)" ::: "memory");
      } else {
        asm volatile("s_waitcnt vmcnt(0)" ::: "memory");
      }
      __builtin_amdgcn_s_barrier();
      __builtin_amdgcn_sched_barrier(0);  // nothing crosses the barrier
    }
    bi = (bi == 2) ? 0 : bi + 1;
    bs = (bs == 2) ? 0 : bs + 1;
  }
#undef STAGE_CHUNK

  // reduce max over the 16 column-lanes of each quad
#pragma unroll
  for (int o = 1; o < 16; o <<= 1) {
#pragma unroll
    for (int r = 0; r < 4; r++) vmax[r] = fmaxf(vmax[r], __shfl_xor(vmax[r], o, 64));
  }
  // rows held by this quad are tokens q*4 + r
  if (mr == 0) {
#pragma unroll
    for (int r = 0; r < 4; r++) {
      const float nr = nrmS[wave][q * 4 + r];
      m_out[tokBase + q * 4 + r] = vmax[r] / fmaxf(sqrtf(nr), 1e-8f);
    }
  }
}

// ---------------------------------------------------------------------------
// Kernel 3: softmax over S per batch. grid = B blocks x 256 threads.
// ---------------------------------------------------------------------------
__global__ __launch_bounds__(256) void k_softmax(const float* __restrict__ m,
                                                 float* __restrict__ beta) {
  const int b = blockIdx.x;
  const int tid = threadIdx.x;
  const float* mb = m + (size_t)b * SS;
  const float v0 = mb[tid];
  const float v1 = mb[tid + 256];
  float mx = fmaxf(v0, v1);
#pragma unroll
  for (int o = 32; o > 0; o >>= 1) mx = fmaxf(mx, __shfl_xor(mx, o, 64));
  __shared__ float wred[4];
  if ((tid & 63) == 0) wred[tid >> 6] = mx;
  __syncthreads();
  mx = fmaxf(fmaxf(wred[0], wred[1]), fmaxf(wred[2], wred[3]));
  const float e0 = __expf(v0 - mx);
  const float e1 = __expf(v1 - mx);
  float s = e0 + e1;
#pragma unroll
  for (int o = 32; o > 0; o >>= 1) s += __shfl_xor(s, o, 64);
  __syncthreads();  // wred reuse hazard
  if ((tid & 63) == 0) wred[tid >> 6] = s;
  __syncthreads();
  s = wred[0] + wred[1] + wred[2] + wred[3];
  const float inv = 1.f / s;
  float* bb = beta + (size_t)b * SS;
  bb[tid] = e0 * inv;
  bb[tid + 256] = e1 * inv;
}

// ---------------------------------------------------------------------------
// Kernel 4: partial z over (batch, s-chunk). grid = B*nsc x 192 threads.
// Thread owns one float4 of D; second (and last) full read of V, coalesced.
// ---------------------------------------------------------------------------
__global__ __launch_bounds__(192) void k_zpart(const float* __restrict__ V,
                                               const float* __restrict__ beta,
                                               float* __restrict__ zpart,
                                               int spc, int nsc) {
  const int blk = blockIdx.x;
  const int b = blk / nsc;
  const int sc = blk % nsc;
  const int tid = threadIdx.x;
  const float* vb = V + ((size_t)b * SS + (size_t)sc * spc) * DD + tid * 4;
  const float* bb = beta + (size_t)b * SS + (size_t)sc * spc;
  float4 acc = {0.f, 0.f, 0.f, 0.f};
#pragma unroll 4
  for (int s = 0; s < spc; s++) {
    const float w = bb[s];
    const float4 x = *(const float4*)(vb + (size_t)s * DD);
    acc.x += w * x.x; acc.y += w * x.y; acc.z += w * x.z; acc.w += w * x.w;
  }
  *(float4*)(zpart + (size_t)blk * DD + tid * 4) = acc;
}

// ---------------------------------------------------------------------------
// Kernel 5: reduce z-partials -> z (to out), then out = z @ fc_w^T + fc_b.
// grid = 2*B blocks (b, class-half) x 256 threads; fc_w L2/L3-resident.
// ---------------------------------------------------------------------------
__global__ __launch_bounds__(256) void k_final(const float* __restrict__ zpart,
                                               const float* __restrict__ fc_w,
                                               const float* __restrict__ fc_b,
                                               float* __restrict__ out,
                                               float* __restrict__ zout,
                                               int nsc) {
  const int b = blockIdx.x >> 1;
  const int half = blockIdx.x & 1;
  const int tid = threadIdx.x;
  __shared__ float zs[DD];
  for (int i = tid; i < DD; i += 256) {
    float s = 0.f;
    for (int sc = 0; sc < nsc; sc++) s += zpart[((size_t)b * nsc + sc) * DD + i];
    zs[i] = s;
    if (half == 0) zout[(size_t)b * DD + i] = s;
  }
  __syncthreads();
  const int c = half * 256 + tid;
  const float4* w = (const float4*)(fc_w + (size_t)c * DD);
  float acc = 0.f;
  for (int d4 = 0; d4 < DD / 4; d4++) {
    const float4 ww = w[d4];
    acc += ww.x * zs[d4 * 4] + ww.y * zs[d4 * 4 + 1] +
           ww.z * zs[d4 * 4 + 2] + ww.w * zs[d4 * 4 + 3];
  }
  out[(size_t)b * CC + c] = acc + fc_b[c];
}

// ---------------------------------------------------------------------------
extern "C" void kernel_launch(void* const* d_in, const int* in_sizes, int n_in,
                              void* d_out, int out_size, void* d_ws, size_t ws_size,
                              hipStream_t stream) {
  const float* V  = (const float*)d_in[0];  // [64,512,768]
  const float* L  = (const float*)d_in[1];  // [512,768]
  const float* fw = (const float*)d_in[2];  // [512,768]
  const float* fb = (const float*)d_in[3];  // [512]
  float* out = (float*)d_out;               // [64*512] out, then [64*768] z

  char* ws = (char*)d_ws;
  unsigned short* Lnb = (unsigned short*)ws;            // 786432 B (frag-linear)
  float* m     = (float*)(ws + 786432);                 // 131072 B
  float* beta  = (float*)(ws + 917504);                 // 131072 B
  float* zpart = (float*)(ws + 1048576);                // nsc*64*768*4 B

  // 16 s-chunks (4 MB total ws) if the workspace allows, else 8 (2.5 MB)
  const int nsc = (ws_size >= (size_t)1048576 + (size_t)16 * BB * DD * 4) ? 16 : 8;
  const int spc = SS / nsc;

  k_label_norm<<<CC, 256, 0, stream>>>(L, Lnb);
  k_sims_max<<<512, 256, 0, stream>>>(V, Lnb, m);
  k_softmax<<<BB, 256, 0, stream>>>(m, beta);
  k_zpart<<<BB * nsc, 192, 0, stream>>>(V, beta, zpart, spc, nsc);
  k_final<<<2 * BB, 256, 0, stream>>>(zpart, fw, fb, out, out + BB * CC, nsc);
}

// Round 7
// 251.770 us; speedup vs baseline: 1.0576x; 1.0576x over previous
//
#include <hip/hip_runtime.h>
#include <cstdint>
#include <cstddef>

// Problem dims (fixed by the reference): B=64, S=512, D=768, C=512
#define BB 64
#define SS 512
#define DD 768
#define CC 512

typedef __attribute__((ext_vector_type(8))) short short8;
typedef __attribute__((ext_vector_type(4))) float f32x4;

#define GLOBAL_AS __attribute__((address_space(1)))
#define LDS_AS __attribute__((address_space(3)))

// float -> bf16 bits, round-to-nearest-even
static __device__ __forceinline__ unsigned short f2bf(float f) {
  union { float f; unsigned u; } v; v.f = f;
  unsigned u = v.u;
  u += 0x7FFFu + ((u >> 16) & 1u);
  return (unsigned short)(u >> 16);
}

// async 16B/lane global->LDS copy (wave-uniform LDS base + lane*16)
static __device__ __forceinline__ void async_copy16(const void* g, void* l) {
  __builtin_amdgcn_global_load_lds((const GLOBAL_AS void*)g, (LDS_AS void*)l,
                                   16, 0, 0);
}

// ---------------------------------------------------------------------------
// Kernel 1: normalize label embeddings -> bf16, FRAGMENT-LINEAR layout.
// Per 16-class chunk (chunk = c>>4), element [class mr=c&15][d] is stored at
// ushort offset  chunk*12288 + kc*512 + q*128 + mr*8 + j   where
// kc = d>>5, q = (d>>3)&3, j = d&7.
// The 64 lanes of a wave reading MFMA B-fragments for K-slice kc then read
// 1024 CONSECUTIVE bytes (addr = lane*16 + kc*1024): zero bank conflicts
// (verified round 4: SQ_LDS_BANK_CONFLICT 6.29M -> 0).
// ---------------------------------------------------------------------------
__global__ __launch_bounds__(256) void k_label_norm(const float* __restrict__ L,
                                                    unsigned short* __restrict__ Lnb) {
  const int c = blockIdx.x;
  const int tid = threadIdx.x;
  const float* row = L + (size_t)c * DD;
  float v[3];
  float s = 0.f;
#pragma unroll
  for (int k = 0; k < 3; k++) { v[k] = row[tid + 256 * k]; s += v[k] * v[k]; }
#pragma unroll
  for (int o = 32; o > 0; o >>= 1) s += __shfl_xor(s, o, 64);
  __shared__ float wsum[4];
  if ((tid & 63) == 0) wsum[tid >> 6] = s;
  __syncthreads();
  const float tot = wsum[0] + wsum[1] + wsum[2] + wsum[3];
  const float inv = 1.f / fmaxf(sqrtf(tot), 1e-8f);
  unsigned short* ochunk = Lnb + (size_t)(c >> 4) * (16 * DD);
  const int mr = c & 15;
#pragma unroll
  for (int k = 0; k < 3; k++) {
    const int d = tid + 256 * k;
    const int kc = d >> 5;
    const int q = (d >> 3) & 3;
    const int j = d & 7;
    ochunk[kc * 512 + q * 128 + mr * 8 + j] = f2bf(v[k] * inv);
  }
}

// ---------------------------------------------------------------------------
// Kernel 2: m[b,s] = max_c dot(V[b,s,:], Ln[c,:]) / max(||V||,eps)
// 512 blocks x 4 waves x 16 tokens; A-fragments (24 x short8 = 96 VGPR) in
// registers; fragment-linear Lnb (round 4: zero bank conflicts).
// HARD CONSTRAINT: VGPR <= 128 (crossing it halved occupancy in r3 AND r6).
// Round 7: counted-vmcnt 3-buffer pipeline, REBUILT for zero marginal VGPR
// after r6's runtime-indexed version cost +20 VGPR (148) and regressed:
//  - static buffer indices via a 3-phase unrolled loop body (LDS bases are
//    compile-time immediates, not registers);
//  - one incrementing wave-uniform src pointer (SGPR) for chunk staging;
//  - bf[4] register pipeline dropped (proven null in r5; -16 VGPR).
// Schedule per phase cc: stage(chunk cc+2) ; compute(buf[cc%3]) ;
// s_waitcnt vmcnt(6) ; s_barrier ; sched_barrier(0).
// vmcnt(6) = keep the 6 just-issued loads (chunk cc+2, 6 per wave) in
// flight across the barrier; chunk cc+1's 6 (issued last phase) are
// verified retired -> staging latency hides under a full compute phase
// instead of the per-iteration vmcnt(0) drain of __syncthreads.
// ---------------------------------------------------------------------------
__global__ __launch_bounds__(256) void k_sims_max(const float* __restrict__ V,
                                                  const unsigned short* __restrict__ Lnb,
                                                  float* __restrict__ m_out) {
  const int tid = threadIdx.x;
  const int wave = tid >> 6;
  const int lane = tid & 63;
  const int q = lane >> 4;    // quad 0..3 (K-slice of the fragment)
  const int mr = lane & 15;   // row (token) for A, col (class) for B
  const int64_t tokBase = (int64_t)blockIdx.x * 64 + wave * 16;

  __shared__ unsigned short Bs[3][16 * DD];  // 3 x 24576 B
  __shared__ float nrmS[4][16];

  const int laneByte = lane * 16;

  // stage one 16-class chunk (24 KB) into buffer bufidx; 6 loads per wave
  auto stage = [&](const unsigned short* src, int bufidx) {
    const char* s = (const char*)src;
    char* dst = (char*)&Bs[bufidx][0];
#pragma unroll
    for (int i = wave; i < 24; i += 4)
      async_copy16(s + i * 1024 + laneByte, dst + i * 1024);
  };

  // ---- prologue: stage chunks 0,1 (in flight during A load)
  stage(Lnb, 0);
  stage(Lnb + 16 * DD, 1);

  // ---- load A fragments + squared norm
  const float* arow = V + (tokBase + mr) * DD + q * 8;
  short8 afrag[24];
  float nrm2 = 0.f;
#pragma unroll
  for (int kc = 0; kc < 24; kc++) {
    const float4* p = (const float4*)(arow + kc * 32);
    const float4 x = p[0];
    const float4 y = p[1];
    short8 a;
    a[0] = (short)f2bf(x.x); a[1] = (short)f2bf(x.y);
    a[2] = (short)f2bf(x.z); a[3] = (short)f2bf(x.w);
    a[4] = (short)f2bf(y.x); a[5] = (short)f2bf(y.y);
    a[6] = (short)f2bf(y.z); a[7] = (short)f2bf(y.w);
    afrag[kc] = a;
    nrm2 += x.x * x.x + x.y * x.y + x.z * x.z + x.w * x.w;
    nrm2 += y.x * y.x + y.y * y.y + y.z * y.z + y.w * y.w;
  }
  // lanes {m, m+16, m+32, m+48} each hold 1/4 of token m's sum of squares
  nrm2 += __shfl_xor(nrm2, 16, 64);
  nrm2 += __shfl_xor(nrm2, 32, 64);
  if (q == 0) nrmS[wave][mr] = nrm2;

  __syncthreads();  // full drain once: buf0/buf1 staged + nrmS visible

  f32x4 vmax = {-3e38f, -3e38f, -3e38f, -3e38f};

  // compute one chunk from buffer bufidx (24 ds_read_b128 -> 24 MFMA)
  auto compute = [&](int bufidx) {
    const char* bbase = (const char*)&Bs[bufidx][0] + laneByte;
    f32x4 acc = {0.f, 0.f, 0.f, 0.f};
#pragma unroll
    for (int kc = 0; kc < 24; kc++) {
      const short8 b = *(const short8*)(bbase + kc * 1024);
      acc = __builtin_amdgcn_mfma_f32_16x16x32_bf16(afrag[kc], b, acc, 0, 0, 0);
    }
    vmax[0] = fmaxf(vmax[0], acc[0]);
    vmax[1] = fmaxf(vmax[1], acc[1]);
    vmax[2] = fmaxf(vmax[2], acc[2]);
    vmax[3] = fmaxf(vmax[3], acc[3]);
  };

#define PHASE_BAR(n)                                   \
  asm volatile("s_waitcnt vmcnt(" #n ")" ::: "memory"); \
  __builtin_amdgcn_s_barrier();                         \
  __builtin_amdgcn_sched_barrier(0);

  // main loop: phases cc = 0..29, three statically-indexed phases per trip.
  // srcp walks chunks 2..31 (wave-uniform -> SGPR).
  const unsigned short* srcp = Lnb + (size_t)2 * 16 * DD;
#pragma unroll 1
  for (int ccb = 0; ccb < 30; ccb += 3) {
    // phase ccb+0: reads buf0, stages chunk ccb+2 -> buf2
    stage(srcp, 2); srcp += 16 * DD;
    __builtin_amdgcn_sched_barrier(0);
    compute(0);
    PHASE_BAR(6)
    // phase ccb+1: reads buf1, stages chunk ccb+3 -> buf0
    stage(srcp, 0); srcp += 16 * DD;
    __builtin_amdgcn_sched_barrier(0);
    compute(1);
    PHASE_BAR(6)
    // phase ccb+2: reads buf2, stages chunk ccb+4 -> buf1
    stage(srcp, 1); srcp += 16 * DD;
    __builtin_amdgcn_sched_barrier(0);
    compute(2);
    PHASE_BAR(6)
  }
  // phase 30: reads buf0 (chunk 30); chunk 31 must land before phase 31
  compute(0);
  PHASE_BAR(0)
  // phase 31: reads buf1 (chunk 31)
  compute(1);
#undef PHASE_BAR

  // reduce max over the 16 column-lanes of each quad
#pragma unroll
  for (int o = 1; o < 16; o <<= 1) {
#pragma unroll
    for (int r = 0; r < 4; r++) vmax[r] = fmaxf(vmax[r], __shfl_xor(vmax[r], o, 64));
  }
  // rows held by this quad are tokens q*4 + r
  if (mr == 0) {
#pragma unroll
    for (int r = 0; r < 4; r++) {
      const float nr = nrmS[wave][q * 4 + r];
      m_out[tokBase + q * 4 + r] = vmax[r] / fmaxf(sqrtf(nr), 1e-8f);
    }
  }
}

// ---------------------------------------------------------------------------
// Kernel 3: softmax over S per batch. grid = B blocks x 256 threads.
// ---------------------------------------------------------------------------
__global__ __launch_bounds__(256) void k_softmax(const float* __restrict__ m,
                                                 float* __restrict__ beta) {
  const int b = blockIdx.x;
  const int tid = threadIdx.x;
  const float* mb = m + (size_t)b * SS;
  const float v0 = mb[tid];
  const float v1 = mb[tid + 256];
  float mx = fmaxf(v0, v1);
#pragma unroll
  for (int o = 32; o > 0; o >>= 1) mx = fmaxf(mx, __shfl_xor(mx, o, 64));
  __shared__ float wred[4];
  if ((tid & 63) == 0) wred[tid >> 6] = mx;
  __syncthreads();
  mx = fmaxf(fmaxf(wred[0], wred[1]), fmaxf(wred[2], wred[3]));
  const float e0 = __expf(v0 - mx);
  const float e1 = __expf(v1 - mx);
  float s = e0 + e1;
#pragma unroll
  for (int o = 32; o > 0; o >>= 1) s += __shfl_xor(s, o, 64);
  __syncthreads();  // wred reuse hazard
  if ((tid & 63) == 0) wred[tid >> 6] = s;
  __syncthreads();
  s = wred[0] + wred[1] + wred[2] + wred[3];
  const float inv = 1.f / s;
  float* bb = beta + (size_t)b * SS;
  bb[tid] = e0 * inv;
  bb[tid + 256] = e1 * inv;
}

// ---------------------------------------------------------------------------
// Kernel 4: partial z over (batch, s-chunk). grid = B*nsc x 192 threads.
// Thread owns one float4 of D; second (and last) full read of V, coalesced.
// ---------------------------------------------------------------------------
__global__ __launch_bounds__(192) void k_zpart(const float* __restrict__ V,
                                               const float* __restrict__ beta,
                                               float* __restrict__ zpart,
                                               int spc, int nsc) {
  const int blk = blockIdx.x;
  const int b = blk / nsc;
  const int sc = blk % nsc;
  const int tid = threadIdx.x;
  const float* vb = V + ((size_t)b * SS + (size_t)sc * spc) * DD + tid * 4;
  const float* bb = beta + (size_t)b * SS + (size_t)sc * spc;
  float4 acc = {0.f, 0.f, 0.f, 0.f};
#pragma unroll 4
  for (int s = 0; s < spc; s++) {
    const float w = bb[s];
    const float4 x = *(const float4*)(vb + (size_t)s * DD);
    acc.x += w * x.x; acc.y += w * x.y; acc.z += w * x.z; acc.w += w * x.w;
  }
  *(float4*)(zpart + (size_t)blk * DD + tid * 4) = acc;
}

// ---------------------------------------------------------------------------
// Kernel 5: reduce z-partials -> z (to out), then out = z @ fc_w^T + fc_b.
// grid = 2*B blocks (b, class-half) x 256 threads; fc_w L2/L3-resident.
// ---------------------------------------------------------------------------
__global__ __launch_bounds__(256) void k_final(const float* __restrict__ zpart,
                                               const float* __restrict__ fc_w,
                                               const float* __restrict__ fc_b,
                                               float* __restrict__ out,
                                               float* __restrict__ zout,
                                               int nsc) {
  const int b = blockIdx.x >> 1;
  const int half = blockIdx.x & 1;
  const int tid = threadIdx.x;
  __shared__ float zs[DD];
  for (int i = tid; i < DD; i += 256) {
    float s = 0.f;
    for (int sc = 0; sc < nsc; sc++) s += zpart[((size_t)b * nsc + sc) * DD + i];
    zs[i] = s;
    if (half == 0) zout[(size_t)b * DD + i] = s;
  }
  __syncthreads();
  const int c = half * 256 + tid;
  const float4* w = (const float4*)(fc_w + (size_t)c * DD);
  float acc = 0.f;
  for (int d4 = 0; d4 < DD / 4; d4++) {
    const float4 ww = w[d4];
    acc += ww.x * zs[d4 * 4] + ww.y * zs[d4 * 4 + 1] +
           ww.z * zs[d4 * 4 + 2] + ww.w * zs[d4 * 4 + 3];
  }
  out[(size_t)b * CC + c] = acc + fc_b[c];
}

// ---------------------------------------------------------------------------
extern "C" void kernel_launch(void* const* d_in, const int* in_sizes, int n_in,
                              void* d_out, int out_size, void* d_ws, size_t ws_size,
                              hipStream_t stream) {
  const float* V  = (const float*)d_in[0];  // [64,512,768]
  const float* L  = (const float*)d_in[1];  // [512,768]
  const float* fw = (const float*)d_in[2];  // [512,768]
  const float* fb = (const float*)d_in[3];  // [512]
  float* out = (float*)d_out;               // [64*512] out, then [64*768] z

  char* ws = (char*)d_ws;
  unsigned short* Lnb = (unsigned short*)ws;            // 786432 B (frag-linear)
  float* m     = (float*)(ws + 786432);                 // 131072 B
  float* beta  = (float*)(ws + 917504);                 // 131072 B
  float* zpart = (float*)(ws + 1048576);                // nsc*64*768*4 B

  // 16 s-chunks (4 MB total ws) if the workspace allows, else 8 (2.5 MB)
  const int nsc = (ws_size >= (size_t)1048576 + (size_t)16 * BB * DD * 4) ? 16 : 8;
  const int spc = SS / nsc;

  k_label_norm<<<CC, 256, 0, stream>>>(L, Lnb);
  k_sims_max<<<512, 256, 0, stream>>>(V, Lnb, m);
  k_softmax<<<BB, 256, 0, stream>>>(m, beta);
  k_zpart<<<BB * nsc, 192, 0, stream>>>(V, beta, zpart, spc, nsc);
  k_final<<<2 * BB, 256, 0, stream>>>(zpart, fw, fb, out, out + BB * CC, nsc);
}